// Round 10
// baseline (404.632 us; speedup 1.0000x reference)
//
#include <hip/hip_runtime.h>
#include <hip/hip_bf16.h>
#include <hip/hip_cooperative_groups.h>

namespace cg = cooperative_groups;

typedef unsigned short u16;
typedef unsigned char u8;
typedef short short8 __attribute__((ext_vector_type(8)));
typedef float floatx4 __attribute__((ext_vector_type(4)));
typedef long long i64;

#define BB 4
#define NN 4096
#define CC 256
#define NG 8
#define M_TOT (BB * NN)   // 16384 rows
#define GN_EPS 1e-3f
#define ATT_SCALE 0.0625f
#define MCONST 2.5f
#define LDT 72

__device__ __forceinline__ u16 f2bf(float f) {
  __hip_bfloat16 h = __float2bfloat16(f);
  return __builtin_bit_cast(u16, h);
}
__device__ __forceinline__ float bf2f(u16 u) {
  unsigned int i = ((unsigned int)u) << 16;
  return __builtin_bit_cast(float, i);
}
__device__ __forceinline__ unsigned pack2(float a, float b) {
  return (unsigned)f2bf(a) | ((unsigned)f2bf(b) << 16);
}
__device__ __forceinline__ unsigned pk4f8(float a, float b, float c, float d) {
  unsigned v = __builtin_amdgcn_cvt_pk_fp8_f32(a, b, 0, false);
  v = __builtin_amdgcn_cvt_pk_fp8_f32(c, d, v, true);
  return v;
}
__device__ __forceinline__ u8 f8byte(float a) {
  return (u8)(__builtin_amdgcn_cvt_pk_fp8_f32(a, a, 0, false) & 0xFF);
}

typedef __attribute__((address_space(3))) unsigned int lds_u32;
typedef const __attribute__((address_space(1))) unsigned int glb_u32;
#define ASYNC16(g, l) \
  __builtin_amdgcn_global_load_lds((glb_u32*)(g), (lds_u32*)(l), 16, 0, 0)

struct Params {
  const float* x; const float* gamma; const float* beta;
  const float* Wq; const float* bq; const float* Wk; const float* bk;
  const float* Wv; const float* bv; const float* Wp; const float* bp;
  float* part;
  u16 *wqT, *wkT, *wvT, *wpT;
  u16* xnb;
  u8 *qb, *kb, *vTb;
  u16* aob;
  u8* Opart; float* Lpart;
  float* out;
  int S;
};

// =====================================================================================
// Shared device helpers (used by both mono phases and fallback kernels)
// =====================================================================================

__device__ __forceinline__ void do_stats_task(const Params& P, int task, int t) {
  if (task < 512) {
    int b = task >> 7, chunk = task & 127;
    const float* p = P.x + ((size_t)b * NN + chunk * 32) * CC + t;
    float s = 0.f, ss = 0.f;
    for (int i = 0; i < 32; ++i) { float v = p[(size_t)i * CC]; s += v; ss += v * v; }
    for (int off = 1; off < 32; off <<= 1) { s += __shfl_xor(s, off); ss += __shfl_xor(ss, off); }
    if ((t & 31) == 0) {
      int g = t >> 5;
      P.part[((size_t)task * NG + g) * 2 + 0] = s;
      P.part[((size_t)task * NG + g) * 2 + 1] = ss;
    }
  } else {
    // weight transpose, register-only path (no LDS): each thread handles 8 outputs of one
    // 64x64 tile via strided reads (uncoalesced reads, small matrix -> L2/L3 absorbs)
    int pid = task - 512;
    int y = pid >> 4, tile = pid & 15;
    int o0 = (tile >> 2) * 64, c0 = (tile & 3) * 64;
    const float* W = (y == 0) ? P.Wq : (y == 1) ? P.Wk : (y == 2) ? P.Wv : P.Wp;
    u16* WT = (y == 0) ? P.wqT : (y == 1) ? P.wkT : (y == 2) ? P.wvT : P.wpT;
    int ol = t >> 2, c8 = t & 3;        // 64 o-rows x 4 chunk-pairs
    for (int half = 0; half < 2; ++half) {
      int cbase = c0 + (c8 * 2 + half * 8) * 8;
      int o = o0 + ol;
      uint4 uv;
      unsigned r[8];
      for (int j = 0; j < 8; ++j)
        r[j] = (unsigned)f2bf(W[(size_t)(cbase + j) * CC + o]);
      uv.x = r[0] | (r[1] << 16); uv.y = r[2] | (r[3] << 16);
      uv.z = r[4] | (r[5] << 16); uv.w = r[6] | (r[7] << 16);
      *reinterpret_cast<uint4*>(WT + (size_t)o * CC + cbase) = uv;
    }
  }
}

__device__ __forceinline__ void do_gn_task(const Params& P, int task, int t, float* gnst) {
  int b = task >> 7;
  if (t < 64) {
    int g = t >> 3, j = t & 7;
    float s = 0.f, ss = 0.f;
    for (int ch = j; ch < 128; ch += 8) {
      size_t idx = (((size_t)(b * 128 + ch)) * NG + g) * 2;
      s += P.part[idx]; ss += P.part[idx + 1];
    }
    for (int off = 1; off < 8; off <<= 1) { s += __shfl_xor(s, off); ss += __shfl_xor(ss, off); }
    if (j == 0) {
      const float cnt = (float)(NN * (CC / NG));
      float mean = s / cnt;
      float var = ss / cnt - mean * mean;
      gnst[g * 2] = mean;
      gnst[g * 2 + 1] = rsqrtf(var + GN_EPS);
    }
  }
  __syncthreads();
  int row0 = task * 32;
#pragma unroll
  for (int it = 0; it < 8; ++it) {
    int idx = t + it * 256;
    int rl = idx >> 6, c4 = idx & 63;
    int g = c4 >> 3;
    float mean = gnst[g * 2], rstd = gnst[g * 2 + 1];
    size_t gidx = (size_t)(row0 + rl) * 64 + c4;
    float4 v = reinterpret_cast<const float4*>(P.x)[gidx];
    float4 gm = reinterpret_cast<const float4*>(P.gamma)[c4];
    float4 bt = reinterpret_cast<const float4*>(P.beta)[c4];
    ushort4 o;
    o.x = f2bf((v.x - mean) * rstd * gm.x + bt.x);
    o.y = f2bf((v.y - mean) * rstd * gm.y + bt.y);
    o.z = f2bf((v.z - mean) * rstd * gm.z + bt.z);
    o.w = f2bf((v.w - mean) * rstd * gm.w + bt.w);
    reinterpret_cast<ushort4*>(P.xnb)[gidx] = o;
  }
  __syncthreads();
}

// QKV GEMM tile m64 x n128 (task in [0,1536)); POOL >= (64+128)*LDT u16
__device__ __forceinline__ void do_qkv_task(const Params& P, int task, int t, u16* POOL) {
  u16* Asp = POOL;
  u16* Bsp = POOL + 64 * LDT;
  u16* Cs = POOL;                       // aliased at epilogue
  int w = t >> 6, lane = t & 63, lo = lane & 15, hi = lane >> 4;
  int wm = (w >> 1) * 32, wn = (w & 1) * 64;
  int m0 = (task & 255) * 64;
  int rest = task >> 8;                 // 0..5
  int widx = rest >> 1;
  int n0 = (rest & 1) * 128;
  const u16* wT = (widx == 0) ? P.wqT : (widx == 1) ? P.wkT : P.wvT;
  const float* bias = (widx == 0) ? P.bq : (widx == 1) ? P.bk : P.bv;
  floatx4 acc[2][4];
  for (int i = 0; i < 2; ++i) for (int j = 0; j < 4; ++j) acc[i][j] = (floatx4){0.f, 0.f, 0.f, 0.f};
  for (int kt = 0; kt < 4; ++kt) {
    int k0 = kt * 64;
    __syncthreads();
    for (int i = 0; i < 2; ++i) {
      int c = t + i * 256, r = c >> 3, c8 = c & 7;
      *reinterpret_cast<uint4*>(Asp + r * LDT + c8 * 8) =
          *reinterpret_cast<const uint4*>(P.xnb + (size_t)(m0 + r) * CC + k0 + c8 * 8);
    }
    for (int i = 0; i < 4; ++i) {
      int c = t + i * 256, r = c >> 3, c8 = c & 7;
      *reinterpret_cast<uint4*>(Bsp + r * LDT + c8 * 8) =
          *reinterpret_cast<const uint4*>(wT + (size_t)(n0 + r) * CC + k0 + c8 * 8);
    }
    __syncthreads();
    for (int k32 = 0; k32 < 2; ++k32) {
      short8 af[2], bfr[4];
      for (int mt = 0; mt < 2; ++mt)
        af[mt] = *reinterpret_cast<const short8*>(Asp + (wm + mt * 16 + lo) * LDT + k32 * 32 + hi * 8);
      for (int nt = 0; nt < 4; ++nt)
        bfr[nt] = *reinterpret_cast<const short8*>(Bsp + (wn + nt * 16 + lo) * LDT + k32 * 32 + hi * 8);
      for (int mt = 0; mt < 2; ++mt)
        for (int nt = 0; nt < 4; ++nt)
          acc[mt][nt] = __builtin_amdgcn_mfma_f32_16x16x32_bf16(af[mt], bfr[nt], acc[mt][nt], 0, 0, 0);
    }
  }
  __syncthreads();
  for (int mt = 0; mt < 2; ++mt)
    for (int nt = 0; nt < 4; ++nt)
      for (int r = 0; r < 4; ++r) {
        int rr = wm + mt * 16 + hi * 4 + r;
        int cc2 = wn + nt * 16 + lo;
        Cs[rr * 130 + cc2] = f2bf(acc[mt][nt][r] + bias[n0 + cc2]);
      }
  __syncthreads();
  if (widx < 2) {
    u8* outp = (widx == 0) ? P.qb : P.kb;
    for (int j = 0; j < 4; ++j) {
      int c = t + j * 256;
      int row = c >> 4, chl = c & 15;
      const u16* sp = Cs + row * 130 + chl * 8;
      uint2 val;
      val.x = pk4f8(bf2f(sp[0]), bf2f(sp[1]), bf2f(sp[2]), bf2f(sp[3]));
      val.y = pk4f8(bf2f(sp[4]), bf2f(sp[5]), bf2f(sp[6]), bf2f(sp[7]));
      int rowg = m0 + row;
      int chg = (n0 >> 3) + chl;
      int chs = (widx == 0) ? chg : ((chg + 2 * (rowg & 15)) & 31);
      *reinterpret_cast<uint2*>(outp + (size_t)rowg * CC + chs * 8) = val;
    }
  } else {
    int dloc = t & 127, tt = t >> 7;
    int dglob = n0 + dloc;
    int rot = (dglob >> 1) & 3;
    uint2 arr[4];
    for (int g = 0; g < 4; ++g) {
      int base = tt * 32 + 4 * g;
      unsigned w0 = pk4f8(bf2f(Cs[(base + 0) * 130 + dloc]), bf2f(Cs[(base + 1) * 130 + dloc]),
                          bf2f(Cs[(base + 2) * 130 + dloc]), bf2f(Cs[(base + 3) * 130 + dloc]));
      unsigned w1 = pk4f8(bf2f(Cs[(base + 16) * 130 + dloc]), bf2f(Cs[(base + 17) * 130 + dloc]),
                          bf2f(Cs[(base + 18) * 130 + dloc]), bf2f(Cs[(base + 19) * 130 + dloc]));
      arr[(g + rot) & 3] = (uint2){w0, w1};
    }
    int tokg = m0 + tt * 32;
    int bb = tokg >> 12, tk2 = tokg & (NN - 1);
    u8* dst = P.vTb + ((size_t)(bb * CC + dglob)) * NN + tk2;
    *reinterpret_cast<uint4*>(dst) = (uint4){arr[0].x, arr[0].y, arr[1].x, arr[1].y};
    *reinterpret_cast<uint4*>(dst + 16) = (uint4){arr[2].x, arr[2].y, arr[3].x, arr[3].y};
  }
  __syncthreads();
}

// fa task (task in [0, 32*BB*S)); POOL >= 16 KB
__device__ __forceinline__ void do_fa_task(const Params& P, int task, int t, u8* POOL) {
  u8* Ks = POOL;
  u8* vTs = POOL + 8192;
  int w = t >> 6, lane = t & 63, lo = lane & 15, hi = lane >> 4;
  int qtile = task & 31, by = task >> 5;
  int S = P.S;
  int b = by / S, split = by - b * S;
  int qw = qtile * 128 + w * 32;

  i64 qf[2][8];
#pragma unroll
  for (int qg = 0; qg < 2; ++qg) {
    const u8* qrow = P.qb + ((size_t)(b * NN + qw + qg * 16 + lo)) * CC;
#pragma unroll
    for (int ds = 0; ds < 8; ++ds)
      qf[qg][ds] = *reinterpret_cast<const i64*>(qrow + ds * 32 + hi * 8);
  }
  floatx4 oacc[2][16];
#pragma unroll
  for (int qg = 0; qg < 2; ++qg)
#pragma unroll
    for (int dt = 0; dt < 16; ++dt) oacc[qg][dt] = (floatx4){0.f, 0.f, 0.f, 0.f};
  float lacc[2] = {0.f, 0.f};

  const int TILES = NN / 32;
  int jt0 = split * (TILES / S), jt1 = jt0 + TILES / S;
  const u8* kb_b = P.kb + (size_t)b * NN * CC;
  const u8* vb_b = P.vTb + (size_t)b * CC * NN;

  for (int jt = jt0; jt < jt1; ++jt) {
    int j0 = jt * 32;
    __syncthreads();
    {
      const u8* gk = kb_b + (size_t)j0 * CC;
#pragma unroll
      for (int rnd = 0; rnd < 2; ++rnd) {
        int o = (w * 2 + rnd) * 1024;
        ASYNC16(gk + o + lane * 16, Ks + o);
      }
#pragma unroll
      for (int rnd = 0; rnd < 2; ++rnd) {
        int o = (w * 2 + rnd) * 1024;
        int o16 = o + lane * 16;
        const u8* gv = vb_b + (size_t)(o16 >> 5) * NN + j0 + (o16 & 31);
        ASYNC16(gv, vTs + o);
      }
    }
    __syncthreads();

    floatx4 s[2][2];
#pragma unroll
    for (int qg = 0; qg < 2; ++qg)
#pragma unroll
      for (int st = 0; st < 2; ++st) s[qg][st] = (floatx4){0.f, 0.f, 0.f, 0.f};
#pragma unroll
    for (int ds = 0; ds < 8; ++ds) {
      int ch = ds * 4 + hi;
      int pch = (ch + 2 * lo) & 31;
      i64 k0 = *reinterpret_cast<const i64*>(Ks + lo * 256 + pch * 8);
      i64 k1 = *reinterpret_cast<const i64*>(Ks + (16 + lo) * 256 + pch * 8);
#pragma unroll
      for (int qg = 0; qg < 2; ++qg) {
        s[qg][0] = __builtin_amdgcn_mfma_f32_16x16x32_fp8_fp8(k0, qf[qg][ds], s[qg][0], 0, 0, 0);
        s[qg][1] = __builtin_amdgcn_mfma_f32_16x16x32_fp8_fp8(k1, qf[qg][ds], s[qg][1], 0, 0, 0);
      }
    }
    i64 pA[2];
#pragma unroll
    for (int qg = 0; qg < 2; ++qg) {
      float p0 = __expf(fmaf(s[qg][0][0], ATT_SCALE, -MCONST));
      float p1 = __expf(fmaf(s[qg][0][1], ATT_SCALE, -MCONST));
      float p2 = __expf(fmaf(s[qg][0][2], ATT_SCALE, -MCONST));
      float p3 = __expf(fmaf(s[qg][0][3], ATT_SCALE, -MCONST));
      float p4 = __expf(fmaf(s[qg][1][0], ATT_SCALE, -MCONST));
      float p5 = __expf(fmaf(s[qg][1][1], ATT_SCALE, -MCONST));
      float p6 = __expf(fmaf(s[qg][1][2], ATT_SCALE, -MCONST));
      float p7 = __expf(fmaf(s[qg][1][3], ATT_SCALE, -MCONST));
      lacc[qg] += (p0 + p1 + p2 + p3) + (p4 + p5 + p6 + p7);
      uint2 uu;
      uu.x = pk4f8(p0, p1, p2, p3);
      uu.y = pk4f8(p4, p5, p6, p7);
      pA[qg] = __builtin_bit_cast(i64, uu);
    }
#pragma unroll
    for (int dt = 0; dt < 16; ++dt) {
      int d = dt * 16 + lo;
      int gp = (hi + ((d >> 1) & 3)) & 3;
      i64 vf = *reinterpret_cast<const i64*>(vTs + d * 32 + gp * 8);
      oacc[0][dt] = __builtin_amdgcn_mfma_f32_16x16x32_fp8_fp8(pA[0], vf, oacc[0][dt], 0, 0, 0);
      oacc[1][dt] = __builtin_amdgcn_mfma_f32_16x16x32_fp8_fp8(pA[1], vf, oacc[1][dt], 0, 0, 0);
    }
  }

#pragma unroll
  for (int qg = 0; qg < 2; ++qg) {
    lacc[qg] += __shfl_xor(lacc[qg], 16);
    lacc[qg] += __shfl_xor(lacc[qg], 32);
  }

  if (P.S == 1) {
#pragma unroll
    for (int qg = 0; qg < 2; ++qg) {
      float inv[4];
#pragma unroll
      for (int r = 0; r < 4; ++r) inv[r] = 1.0f / __shfl(lacc[qg], 4 * hi + r);
#pragma unroll
      for (int dt = 0; dt < 16; ++dt)
#pragma unroll
        for (int r = 0; r < 4; ++r) {
          size_t row = (size_t)(b * NN + qw + qg * 16 + 4 * hi + r);
          P.aob[row * CC + dt * 16 + lo] = f2bf(oacc[qg][dt][r] * inv[r]);
        }
    }
  } else {
    if (hi == 0) {
#pragma unroll
      for (int qg = 0; qg < 2; ++qg)
        P.Lpart[(size_t)split * M_TOT + b * NN + qw + qg * 16 + lo] = lacc[qg];
    }
    u8* op = P.Opart + (size_t)split * M_TOT * CC;
#pragma unroll
    for (int qg = 0; qg < 2; ++qg)
#pragma unroll
      for (int dt = 0; dt < 16; ++dt)
#pragma unroll
        for (int r = 0; r < 4; ++r) {
          size_t row = (size_t)(b * NN + qw + qg * 16 + 4 * hi + r);
          op[row * CC + dt * 16 + lo] = f8byte(oacc[qg][dt][r]);
        }
  }
  __syncthreads();
}

// proj task (task in [0,512)); POOL >= (64+128)*LDT u16; linv 64 floats
__device__ __forceinline__ void do_proj_task(const Params& P, int task, int t,
                                             u16* POOL, float* linv) {
  u16* Asp = POOL;
  u16* Bsp = POOL + 64 * LDT;
  int w = t >> 6, lane = t & 63, lo = lane & 15, hi = lane >> 4;
  int S = P.S;
  int m0 = (task & 255) * 64;
  int n0 = (task >> 8) * 128;
  int wm = (w >> 1) * 32, wn = (w & 1) * 64;
  if (S > 1 && t < 64) {
    float l = 0.f;
    for (int sp = 0; sp < S; ++sp) l += P.Lpart[(size_t)sp * M_TOT + m0 + t];
    linv[t] = 1.f / l;
  }
  floatx4 acc[2][4];
  for (int i = 0; i < 2; ++i) for (int j = 0; j < 4; ++j) acc[i][j] = (floatx4){0.f, 0.f, 0.f, 0.f};
  for (int kt = 0; kt < 4; ++kt) {
    int k0 = kt * 64;
    __syncthreads();
    for (int i = 0; i < 2; ++i) {
      int c = t + i * 256, r = c >> 3, c8 = c & 7;
      if (S == 1) {
        *reinterpret_cast<uint4*>(Asp + r * LDT + c8 * 8) =
            *reinterpret_cast<const uint4*>(P.aob + (size_t)(m0 + r) * CC + k0 + c8 * 8);
      } else {
        float f[8] = {0, 0, 0, 0, 0, 0, 0, 0};
        for (int sp = 0; sp < S; ++sp) {
          uint2 uv = *reinterpret_cast<const uint2*>(
              P.Opart + (size_t)sp * M_TOT * CC + (size_t)(m0 + r) * CC + k0 + c8 * 8);
          f[0] += __builtin_amdgcn_cvt_f32_fp8(uv.x, 0);
          f[1] += __builtin_amdgcn_cvt_f32_fp8(uv.x, 1);
          f[2] += __builtin_amdgcn_cvt_f32_fp8(uv.x, 2);
          f[3] += __builtin_amdgcn_cvt_f32_fp8(uv.x, 3);
          f[4] += __builtin_amdgcn_cvt_f32_fp8(uv.y, 0);
          f[5] += __builtin_amdgcn_cvt_f32_fp8(uv.y, 1);
          f[6] += __builtin_amdgcn_cvt_f32_fp8(uv.y, 2);
          f[7] += __builtin_amdgcn_cvt_f32_fp8(uv.y, 3);
        }
        float iv = linv[r];
        uint4 o;
        o.x = pack2(f[0] * iv, f[1] * iv); o.y = pack2(f[2] * iv, f[3] * iv);
        o.z = pack2(f[4] * iv, f[5] * iv); o.w = pack2(f[6] * iv, f[7] * iv);
        *reinterpret_cast<uint4*>(Asp + r * LDT + c8 * 8) = o;
      }
    }
    for (int i = 0; i < 4; ++i) {
      int c = t + i * 256, r = c >> 3, c8 = c & 7;
      *reinterpret_cast<uint4*>(Bsp + r * LDT + c8 * 8) =
          *reinterpret_cast<const uint4*>(P.wpT + (size_t)(n0 + r) * CC + k0 + c8 * 8);
    }
    __syncthreads();
    for (int k32 = 0; k32 < 2; ++k32) {
      short8 af[2], bfr[4];
      for (int mt = 0; mt < 2; ++mt)
        af[mt] = *reinterpret_cast<const short8*>(Asp + (wm + mt * 16 + lo) * LDT + k32 * 32 + hi * 8);
      for (int nt = 0; nt < 4; ++nt)
        bfr[nt] = *reinterpret_cast<const short8*>(Bsp + (wn + nt * 16 + lo) * LDT + k32 * 32 + hi * 8);
      for (int mt = 0; mt < 2; ++mt)
        for (int nt = 0; nt < 4; ++nt)
          acc[mt][nt] = __builtin_amdgcn_mfma_f32_16x16x32_bf16(af[mt], bfr[nt], acc[mt][nt], 0, 0, 0);
    }
  }
  for (int mt = 0; mt < 2; ++mt)
    for (int nt = 0; nt < 4; ++nt)
      for (int r = 0; r < 4; ++r) {
        int row = m0 + wm + mt * 16 + hi * 4 + r;
        int col = n0 + wn + nt * 16 + lo;
        size_t o = (size_t)row * CC + col;
        P.out[o] = acc[mt][nt][r] + P.bp[col] + bf2f(P.xnb[o]);
      }
  __syncthreads();
}

// =====================================================================================
// Monolithic cooperative kernel: grid-stride over tasks in 5 phases
// =====================================================================================
__global__ __launch_bounds__(256, 2) void mono(Params P) {
  cg::grid_group grid = cg::this_grid();
  __shared__ __align__(16) u16 POOL[(64 + 128) * LDT];
  __shared__ float gnst[16];
  __shared__ float linv[64];
  int t = threadIdx.x;
  int nb = gridDim.x;

  for (int task = blockIdx.x; task < 576; task += nb) do_stats_task(P, task, t);
  grid.sync();
  for (int task = blockIdx.x; task < 512; task += nb) do_gn_task(P, task, t, gnst);
  grid.sync();
  for (int task = blockIdx.x; task < 1536; task += nb) do_qkv_task(P, task, t, POOL);
  grid.sync();
  for (int task = blockIdx.x; task < 32 * BB * P.S; task += nb) do_fa_task(P, task, t, (u8*)POOL);
  grid.sync();
  for (int task = blockIdx.x; task < 512; task += nb) do_proj_task(P, task, t, POOL, linv);
}

// =====================================================================================
// Fallback kernels (R8-equivalent, one phase each)
// =====================================================================================
__global__ void fb_stats(Params P) { do_stats_task(P, blockIdx.x, threadIdx.x); }
__global__ __launch_bounds__(256) void fb_gn(Params P) {
  __shared__ float gnst[16];
  do_gn_task(P, blockIdx.x, threadIdx.x, gnst);
}
__global__ __launch_bounds__(256) void fb_qkv(Params P) {
  __shared__ __align__(16) u16 POOL[(64 + 128) * LDT];
  do_qkv_task(P, blockIdx.x, threadIdx.x, POOL);
}
__global__ __launch_bounds__(256, 2) void fb_fa(Params P) {
  __shared__ __align__(16) u8 POOL[16384];
  do_fa_task(P, blockIdx.x, threadIdx.x, POOL);
}
__global__ __launch_bounds__(256) void fb_proj(Params P) {
  __shared__ __align__(16) u16 POOL[(64 + 128) * LDT];
  __shared__ float linv[64];
  do_proj_task(P, blockIdx.x, threadIdx.x, POOL, linv);
}

extern "C" void kernel_launch(void* const* d_in, const int* in_sizes, int n_in,
                              void* d_out, int out_size, void* d_ws, size_t ws_size,
                              hipStream_t stream) {
  (void)in_sizes; (void)n_in; (void)out_size;
  Params P;
  P.x     = (const float*)d_in[0];
  P.gamma = (const float*)d_in[1];
  P.beta  = (const float*)d_in[2];
  P.Wq    = (const float*)d_in[3];
  P.bq    = (const float*)d_in[4];
  P.Wk    = (const float*)d_in[5];
  P.bk    = (const float*)d_in[6];
  P.Wv    = (const float*)d_in[7];
  P.bv    = (const float*)d_in[8];
  P.Wp    = (const float*)d_in[9];
  P.bp    = (const float*)d_in[10];
  P.out = (float*)d_out;

  char* w = (char*)d_ws;
  P.part = (float*)w;                    w += 512 * NG * 2 * 4;
  const size_t SZ = (size_t)M_TOT * CC * 2;
  const size_t SZ8 = (size_t)M_TOT * CC;
  P.xnb = (u16*)w; w += SZ;
  P.qb  = (u8*)w;  w += SZ8;
  P.kb  = (u8*)w;  w += SZ8;
  P.vTb = (u8*)w;  w += SZ8;
  P.aob = (u16*)w; w += SZ;
  P.wqT = (u16*)w; w += (size_t)CC * CC * 2;
  P.wkT = (u16*)w; w += (size_t)CC * CC * 2;
  P.wvT = (u16*)w; w += (size_t)CC * CC * 2;
  P.wpT = (u16*)w; w += (size_t)CC * CC * 2;

  size_t used = (size_t)(w - (char*)d_ws);
  size_t per_split = SZ8 + (size_t)M_TOT * 4 + 256;
  int S = 4;
  if (used + 4 * per_split > ws_size) S = 2;
  if (used + 2 * per_split > ws_size) S = 1;
  P.S = S;
  P.Opart = (u8*)w;                      w += (size_t)S * SZ8;
  P.Lpart = (float*)w;

  // Attempt cooperative mono launch sized by real occupancy; fall back on any failure.
  bool coop_ok = false;
  int occ = 0;
  hipError_t oe = hipOccupancyMaxActiveBlocksPerMultiprocessor(&occ, (const void*)mono, 256, 0);
  if (oe == hipSuccess && occ >= 1) {
    int nblk = occ * 256;                // 256 CUs on MI355X
    if (nblk > 512) nblk = 512;
    void* args[] = { &P };
    hipError_t le = hipLaunchCooperativeKernel((void*)mono, dim3(nblk), dim3(256), args, 0, stream);
    if (le == hipSuccess) coop_ok = true;
    else (void)hipGetLastError();        // clear sticky error
  } else {
    (void)hipGetLastError();
  }

  if (!coop_ok) {
    fb_stats<<<576, 256, 0, stream>>>(P);
    fb_gn<<<512, 256, 0, stream>>>(P);
    fb_qkv<<<1536, 256, 0, stream>>>(P);
    fb_fa<<<32 * BB * S, 256, 0, stream>>>(P);
    fb_proj<<<512, 256, 0, stream>>>(P);
  }
}